// Round 9
// baseline (62.201 us; speedup 1.0000x reference)
//
#include <hip/hip_runtime.h>
#include <hip/hip_bf16.h>

typedef int   v4i __attribute__((ext_vector_type(4)));
typedef float v4f __attribute__((ext_vector_type(4)));

#define HWSZ 3136   // 56*56
#define IMW  56
#define PADW 58     // 56+2 halo
#define PHW  3364   // 58*58
#define CIN  64
#define COUT 128

__device__ __forceinline__ float step_size(float a) {
    a = a > 0.f ? a : 0.f;              // relu(alpha)
    return 2.0f * a / 254.0f;
}

__device__ __forceinline__ int quant1(float x, float s) {
    float v = rintf(x / s);             // round-half-even like jnp.round
    v = fminf(127.f, fmaxf(-127.f, v)); // clip(-127, 127)
    return (int)v;
}

__device__ __forceinline__ unsigned int pack4(int a, int b, int c, int d) {
    return (unsigned int)(a & 255) | ((unsigned int)(b & 255) << 8) |
           ((unsigned int)(c & 255) << 16) | ((unsigned int)(d & 255) << 24);
}

// ---------------- fused quantize (UNCHANGED from R8) ----------------
__global__ __launch_bounds__(256) void quant_kernel(const float* __restrict__ x,
                                                    const float* __restrict__ w,
                                                    const float* __restrict__ alpha_x,
                                                    const float* __restrict__ alpha_w,
                                                    signed char* __restrict__ cx,
                                                    signed char* __restrict__ wt) {
    int t = threadIdx.x;
    int b = blockIdx.x;
    if (b >= 392) {
        if (b >= 680) {
            int q = (b - 680) * 256 + t;
            int n = q / 912;
            int r = q % 912;
            int px = r >> 2, seg = r & 3;
            int ph, pw;
            if (px < 58)       { ph = 0;  pw = px; }
            else if (px < 116) { ph = 57; pw = px - 58; }
            else { int k = px - 116; ph = 1 + (k >> 1); pw = (k & 1) * 57; }
            v4i z = {0, 0, 0, 0};
            *(v4i*)(cx + ((size_t)n * PHW + ph * PADW + pw) * 64 + seg * 16) = z;
            return;
        }
        float s = step_size(alpha_w[0]);
        int j = (b - 392) * 256 + t;   // wt flat index in [tap][o][c]
        int tap = j / 8192;
        int r   = j % 8192;
        int o   = r >> 6;
        int c   = r & 63;
        float v = w[((size_t)o * 64 + c) * 9 + tap];
        wt[j] = (signed char)quant1(v, s);
        return;
    }

    __shared__ unsigned int tile32[64 * 17];
    float s = step_size(alpha_x[0]);
    int nb  = b / 49;
    int hw0 = (b % 49) * 64;
    int g   = t & 15;
    int cq  = t >> 4;
    int p   = t >> 2;
    int seg = t & 3;
    int hw  = hw0 + p;
    int h   = hw / IMW, wq = hw % IMW;
    signed char* cxp = cx + ((size_t)(h + 1) * PADW + (wq + 1)) * 64 + seg * 16;

#pragma unroll
    for (int i = 0; i < 4; ++i) {
        int n = nb * 4 + i;
        const float* xb = x + ((size_t)n * CIN + cq * 4) * HWSZ + hw0 + g * 4;
        v4f f0 = *(const v4f*)(xb);
        v4f f1 = *(const v4f*)(xb + HWSZ);
        v4f f2 = *(const v4f*)(xb + 2 * HWSZ);
        v4f f3 = *(const v4f*)(xb + 3 * HWSZ);
        if (i) __syncthreads();
#pragma unroll
        for (int j = 0; j < 4; ++j) {
            unsigned int u = pack4(quant1(f0[j], s), quant1(f1[j], s),
                                   quant1(f2[j], s), quant1(f3[j], s));
            tile32[(g * 4 + j) * 17 + cq] = u;
        }
        __syncthreads();
        int base = p * 17 + seg * 4;
        v4i val;
        val[0] = (int)tile32[base + 0];
        val[1] = (int)tile32[base + 1];
        val[2] = (int)tile32[base + 2];
        val[3] = (int)tile32[base + 3];
        *(v4i*)(cxp + (size_t)n * PHW * 64) = val;
    }
}

// ---------------- int8 implicit-GEMM conv, wt[tap][o][c] ----------------
// MEASUREMENT BUILD: body repeated 2x behind an opaque asm barrier so the
// dispatch (~54us) outranks the harness poison-fills (~41us) in the rocprof
// top-5 and we finally see conv's MfmaUtil/FETCH/WRITE/Occupancy.
// Second rep recomputes identical acc and stores identical bytes.
__global__ __launch_bounds__(128) void conv_kernel(const signed char* __restrict__ cx,
                                                   const signed char* __restrict__ wt,
                                                   const float* __restrict__ ax,
                                                   const float* __restrict__ aw,
                                                   float* __restrict__ out) {
    float scale = step_size(ax[0]) * step_size(aw[0]);
    int tid  = threadIdx.x;
    int lane = tid & 63;
    int wid  = tid >> 6;
    int row  = lane & 15;
    int kg   = lane >> 4;

    int bid  = blockIdx.x;
    int swz  = (bid & 7) * 196 + (bid >> 3);
    int pbase = swz * 64;
    int obase = wid * 64;

    const signed char* xb[4];
#pragma unroll
    for (int pt = 0; pt < 4; ++pt) {
        int p  = pbase + pt * 16 + row;
        int n  = p / HWSZ;
        int hw = p % HWSZ;
        int h  = hw / IMW, wq = hw % IMW;
        xb[pt] = cx + ((size_t)n * PHW + (h + 1) * PADW + (wq + 1)) * 64 + kg * 16;
    }
    const signed char* wb = wt + (obase + row) * 64 + kg * 16;

#pragma unroll 1
    for (int rep = 0; rep < 2; ++rep) {
        const signed char* xbr0 = xb[0];
        const signed char* xbr1 = xb[1];
        const signed char* xbr2 = xb[2];
        const signed char* xbr3 = xb[3];
        const signed char* wbr  = wb;
        // opaque: prevents CSE of loads/MFMA across reps
        asm volatile("" : "+v"(xbr0), "+v"(xbr1), "+v"(xbr2), "+v"(xbr3), "+v"(wbr));
        const signed char* xr[4] = {xbr0, xbr1, xbr2, xbr3};

        v4i acc[4][4] = {};

#pragma unroll
        for (int tap = 0; tap < 9; ++tap) {
            int doff = ((tap / 3 - 1) * PADW + (tap % 3 - 1)) * 64;
            v4i a[4];
#pragma unroll
            for (int pt = 0; pt < 4; ++pt)
                a[pt] = *(const v4i*)(xr[pt] + doff);
            v4i b[4];
#pragma unroll
            for (int ot = 0; ot < 4; ++ot)
                b[ot] = *(const v4i*)(wbr + tap * (COUT * 64) + ot * (16 * 64));
#pragma unroll
            for (int pt = 0; pt < 4; ++pt)
#pragma unroll
                for (int ot = 0; ot < 4; ++ot)
                    acc[pt][ot] = __builtin_amdgcn_mfma_i32_16x16x64_i8(a[pt], b[ot], acc[pt][ot], 0, 0, 0);
        }

#pragma unroll
        for (int pt = 0; pt < 4; ++pt) {
            int p4 = pbase + pt * 16 + kg * 4;
            int n  = p4 / HWSZ;
            int hw = p4 % HWSZ;
#pragma unroll
            for (int ot = 0; ot < 4; ++ot) {
                int o = obase + ot * 16 + row;
                v4f v;
                v[0] = scale * (float)acc[pt][ot][0];
                v[1] = scale * (float)acc[pt][ot][1];
                v[2] = scale * (float)acc[pt][ot][2];
                v[3] = scale * (float)acc[pt][ot][3];
                *(v4f*)(out + ((size_t)n * COUT + o) * HWSZ + hw) = v;
            }
        }
    }
}

extern "C" void kernel_launch(void* const* d_in, const int* in_sizes, int n_in,
                              void* d_out, int out_size, void* d_ws, size_t ws_size,
                              hipStream_t stream) {
    const float* x  = (const float*)d_in[0];
    const float* w  = (const float*)d_in[1];
    const float* ax = (const float*)d_in[2];
    const float* aw = (const float*)d_in[3];
    float* out = (float*)d_out;

    signed char* cx = (signed char*)d_ws;   // 32*3364*64 = 6,889,472 B (padded NHWC)
    signed char* wt = cx + 6889472;         // 9*128*64   =    73,728 B  [tap][o][c]

    quant_kernel<<<794, 256, 0, stream>>>(x, w, ax, aw, cx, wt);
    conv_kernel<<<1568, 128, 0, stream>>>(cx, wt, ax, aw, out);
}

// Round 10
// 42.806 us; speedup vs baseline: 1.4531x; 1.4531x over previous
//
#include <hip/hip_runtime.h>
#include <hip/hip_bf16.h>

typedef int   v4i __attribute__((ext_vector_type(4)));
typedef float v4f __attribute__((ext_vector_type(4)));

#define HWSZ 3136   // 56*56
#define IMW  56
#define PADW 58     // 56+2 halo
#define PHW  3364   // 58*58
#define CIN  64
#define COUT 128

__device__ __forceinline__ float step_size(float a) {
    a = a > 0.f ? a : 0.f;              // relu(alpha)
    return 2.0f * a / 254.0f;
}

__device__ __forceinline__ int quant1(float x, float s) {
    float v = rintf(x / s);             // round-half-even like jnp.round
    v = fminf(127.f, fmaxf(-127.f, v)); // clip(-127, 127)
    return (int)v;
}

__device__ __forceinline__ unsigned int pack4(int a, int b, int c, int d) {
    return (unsigned int)(a & 255) | ((unsigned int)(b & 255) << 8) |
           ((unsigned int)(c & 255) << 16) | ((unsigned int)(d & 255) << 24);
}

// ---------------- fused quantize (UNCHANGED from R8) ----------------
__global__ __launch_bounds__(256) void quant_kernel(const float* __restrict__ x,
                                                    const float* __restrict__ w,
                                                    const float* __restrict__ alpha_x,
                                                    const float* __restrict__ alpha_w,
                                                    signed char* __restrict__ cx,
                                                    signed char* __restrict__ wt) {
    int t = threadIdx.x;
    int b = blockIdx.x;
    if (b >= 392) {
        if (b >= 680) {
            int q = (b - 680) * 256 + t;
            int n = q / 912;
            int r = q % 912;
            int px = r >> 2, seg = r & 3;
            int ph, pw;
            if (px < 58)       { ph = 0;  pw = px; }
            else if (px < 116) { ph = 57; pw = px - 58; }
            else { int k = px - 116; ph = 1 + (k >> 1); pw = (k & 1) * 57; }
            v4i z = {0, 0, 0, 0};
            *(v4i*)(cx + ((size_t)n * PHW + ph * PADW + pw) * 64 + seg * 16) = z;
            return;
        }
        float s = step_size(alpha_w[0]);
        int j = (b - 392) * 256 + t;   // wt flat index in [tap][o][c]
        int tap = j / 8192;
        int r   = j % 8192;
        int o   = r >> 6;
        int c   = r & 63;
        float v = w[((size_t)o * 64 + c) * 9 + tap];
        wt[j] = (signed char)quant1(v, s);
        return;
    }

    __shared__ unsigned int tile32[64 * 17];
    float s = step_size(alpha_x[0]);
    int nb  = b / 49;
    int hw0 = (b % 49) * 64;
    int g   = t & 15;
    int cq  = t >> 4;
    int p   = t >> 2;
    int seg = t & 3;
    int hw  = hw0 + p;
    int h   = hw / IMW, wq = hw % IMW;
    signed char* cxp = cx + ((size_t)(h + 1) * PADW + (wq + 1)) * 64 + seg * 16;

#pragma unroll
    for (int i = 0; i < 4; ++i) {
        int n = nb * 4 + i;
        const float* xb = x + ((size_t)n * CIN + cq * 4) * HWSZ + hw0 + g * 4;
        v4f f0 = *(const v4f*)(xb);
        v4f f1 = *(const v4f*)(xb + HWSZ);
        v4f f2 = *(const v4f*)(xb + 2 * HWSZ);
        v4f f3 = *(const v4f*)(xb + 3 * HWSZ);
        if (i) __syncthreads();
#pragma unroll
        for (int j = 0; j < 4; ++j) {
            unsigned int u = pack4(quant1(f0[j], s), quant1(f1[j], s),
                                   quant1(f2[j], s), quant1(f3[j], s));
            tile32[(g * 4 + j) * 17 + cq] = u;
        }
        __syncthreads();
        int base = p * 17 + seg * 4;
        v4i val;
        val[0] = (int)tile32[base + 0];
        val[1] = (int)tile32[base + 1];
        val[2] = (int)tile32[base + 2];
        val[3] = (int)tile32[base + 3];
        *(v4i*)(cxp + (size_t)n * PHW * 64) = val;
    }
}

// ---------------- int8 implicit-GEMM conv: pipelined + 2x TLP ----------------
// wave tile = 32 px x 64 o (acc[2][4] = 32 VGPR) -> 6272 waves (~6/SIMD demanded)
// block = 256 thr (4 waves = 64 px x 128 o), grid = 1568 (1568%8==0, XCD swizzle)
// Explicit 1-tap register double-buffer: tap+1 loads issue before tap's MFMAs.
__global__ __launch_bounds__(256) void conv_kernel(const signed char* __restrict__ cx,
                                                   const signed char* __restrict__ wt,
                                                   const float* __restrict__ ax,
                                                   const float* __restrict__ aw,
                                                   float* __restrict__ out) {
    float scale = step_size(ax[0]) * step_size(aw[0]);
    int tid  = threadIdx.x;
    int lane = tid & 63;
    int wid  = tid >> 6;    // 0..3
    int row  = lane & 15;
    int kg   = lane >> 4;
    int wp   = wid >> 1;    // px subtile (0..1)
    int wo   = wid & 1;     // o half

    int bid  = blockIdx.x;
    int swz  = (bid & 7) * 196 + (bid >> 3);
    int pbase = swz * 64 + wp * 32;
    int obase = wo * 64;

    const signed char* xb[2];
#pragma unroll
    for (int pt = 0; pt < 2; ++pt) {
        int p  = pbase + pt * 16 + row;
        int n  = p / HWSZ;
        int hw = p % HWSZ;
        int h  = hw / IMW, wq = hw % IMW;
        xb[pt] = cx + ((size_t)n * PHW + (h + 1) * PADW + (wq + 1)) * 64 + kg * 16;
    }
    const signed char* wb = wt + (obase + row) * 64 + kg * 16;

    v4i a[2][2], b[2][4];
    v4i acc[2][4] = {};

    // preload tap 0 into buffer 0
#pragma unroll
    for (int pt = 0; pt < 2; ++pt)
        a[0][pt] = *(const v4i*)(xb[pt] + ((0 / 3 - 1) * PADW + (0 % 3 - 1)) * 64);
#pragma unroll
    for (int ot = 0; ot < 4; ++ot)
        b[0][ot] = *(const v4i*)(wb + 0 * (COUT * 64) + ot * (16 * 64));

#pragma unroll
    for (int tap = 0; tap < 9; ++tap) {
        int cur = tap & 1, nxt = cur ^ 1;   // compile-time under full unroll
        if (tap < 8) {
            int t1 = tap + 1;
            int doff = ((t1 / 3 - 1) * PADW + (t1 % 3 - 1)) * 64;
#pragma unroll
            for (int pt = 0; pt < 2; ++pt)
                a[nxt][pt] = *(const v4i*)(xb[pt] + doff);
#pragma unroll
            for (int ot = 0; ot < 4; ++ot)
                b[nxt][ot] = *(const v4i*)(wb + t1 * (COUT * 64) + ot * (16 * 64));
        }
#pragma unroll
        for (int pt = 0; pt < 2; ++pt)
#pragma unroll
            for (int ot = 0; ot < 4; ++ot)
                acc[pt][ot] = __builtin_amdgcn_mfma_i32_16x16x64_i8(a[cur][pt], b[cur][ot], acc[pt][ot], 0, 0, 0);
    }

    // epilogue: D row = (lane>>4)*4+reg = pixel, col = lane&15 = o
#pragma unroll
    for (int pt = 0; pt < 2; ++pt) {
        int p4 = pbase + pt * 16 + kg * 4;
        int n  = p4 / HWSZ;
        int hw = p4 % HWSZ;
#pragma unroll
        for (int ot = 0; ot < 4; ++ot) {
            int o = obase + ot * 16 + row;
            v4f v;
            v[0] = scale * (float)acc[pt][ot][0];
            v[1] = scale * (float)acc[pt][ot][1];
            v[2] = scale * (float)acc[pt][ot][2];
            v[3] = scale * (float)acc[pt][ot][3];
            *(v4f*)(out + ((size_t)n * COUT + o) * HWSZ + hw) = v;
        }
    }
}

extern "C" void kernel_launch(void* const* d_in, const int* in_sizes, int n_in,
                              void* d_out, int out_size, void* d_ws, size_t ws_size,
                              hipStream_t stream) {
    const float* x  = (const float*)d_in[0];
    const float* w  = (const float*)d_in[1];
    const float* ax = (const float*)d_in[2];
    const float* aw = (const float*)d_in[3];
    float* out = (float*)d_out;

    signed char* cx = (signed char*)d_ws;   // 32*3364*64 = 6,889,472 B (padded NHWC)
    signed char* wt = cx + 6889472;         // 9*128*64   =    73,728 B  [tap][o][c]

    quant_kernel<<<794, 256, 0, stream>>>(x, w, ax, aw, cx, wt);
    conv_kernel<<<1568, 256, 0, stream>>>(cx, wt, ax, aw, out);
}

// Round 11
// 36.116 us; speedup vs baseline: 1.7223x; 1.1852x over previous
//
#include <hip/hip_runtime.h>
#include <hip/hip_bf16.h>

typedef int   v4i __attribute__((ext_vector_type(4)));
typedef float v4f __attribute__((ext_vector_type(4)));

#define HWSZ 3136   // 56*56
#define IMW  56
#define PADW 58     // 56+2 halo
#define PHW  3364   // 58*58
#define CIN  64
#define COUT 128
#define WT_HALF 36864   // 9 taps * 64 o * 64 c

__device__ __forceinline__ float step_size(float a) {
    a = a > 0.f ? a : 0.f;              // relu(alpha)
    return 2.0f * a / 254.0f;
}

__device__ __forceinline__ int quant1(float x, float s) {
    float v = rintf(x / s);             // round-half-even like jnp.round
    v = fminf(127.f, fmaxf(-127.f, v)); // clip(-127, 127)
    return (int)v;
}

__device__ __forceinline__ unsigned int pack4(int a, int b, int c, int d) {
    return (unsigned int)(a & 255) | ((unsigned int)(b & 255) << 8) |
           ((unsigned int)(c & 255) << 16) | ((unsigned int)(d & 255) << 24);
}

__device__ __forceinline__ void gload_lds16(const signed char* g, signed char* l) {
    __builtin_amdgcn_global_load_lds(
        (const __attribute__((address_space(1))) void*)g,
        (__attribute__((address_space(3))) void*)l, 16, 0, 0);
}

// ---------------- fused quantize ----------------
// blocks 0..391  : x NCHW fp32 -> padded NHWC int8
// blocks 392..679: w OIHW -> wt[half][tap][o&63][c]
// blocks 680..793: zero the 1-px halo of cx
__global__ __launch_bounds__(256) void quant_kernel(const float* __restrict__ x,
                                                    const float* __restrict__ w,
                                                    const float* __restrict__ alpha_x,
                                                    const float* __restrict__ alpha_w,
                                                    signed char* __restrict__ cx,
                                                    signed char* __restrict__ wt) {
    int t = threadIdx.x;
    int b = blockIdx.x;
    if (b >= 392) {
        if (b >= 680) {
            int q = (b - 680) * 256 + t;
            int n = q / 912;
            int r = q % 912;
            int px = r >> 2, seg = r & 3;
            int ph, pw;
            if (px < 58)       { ph = 0;  pw = px; }
            else if (px < 116) { ph = 57; pw = px - 58; }
            else { int k = px - 116; ph = 1 + (k >> 1); pw = (k & 1) * 57; }
            v4i z = {0, 0, 0, 0};
            *(v4i*)(cx + ((size_t)n * PHW + ph * PADW + pw) * 64 + seg * 16) = z;
            return;
        }
        float s = step_size(alpha_w[0]);
        int j = (b - 392) * 256 + t;   // 73728 total
        int tap = j / 8192;
        int r   = j % 8192;
        int o   = r >> 6;
        int c   = r & 63;
        float v = w[((size_t)o * 64 + c) * 9 + tap];
        // layout: [o>>6][tap][o&63][c]
        wt[(o >> 6) * WT_HALF + tap * 4096 + (o & 63) * 64 + c] = (signed char)quant1(v, s);
        return;
    }

    __shared__ unsigned int tile32[64 * 17];
    float s = step_size(alpha_x[0]);
    int nb  = b / 49;
    int hw0 = (b % 49) * 64;
    int g   = t & 15;
    int cq  = t >> 4;
    int p   = t >> 2;
    int seg = t & 3;
    int hw  = hw0 + p;
    int h   = hw / IMW, wq = hw % IMW;
    signed char* cxp = cx + ((size_t)(h + 1) * PADW + (wq + 1)) * 64 + seg * 16;

#pragma unroll
    for (int i = 0; i < 4; ++i) {
        int n = nb * 4 + i;
        const float* xb = x + ((size_t)n * CIN + cq * 4) * HWSZ + hw0 + g * 4;
        v4f f0 = *(const v4f*)(xb);
        v4f f1 = *(const v4f*)(xb + HWSZ);
        v4f f2 = *(const v4f*)(xb + 2 * HWSZ);
        v4f f3 = *(const v4f*)(xb + 3 * HWSZ);
        if (i) __syncthreads();
#pragma unroll
        for (int j = 0; j < 4; ++j) {
            unsigned int u = pack4(quant1(f0[j], s), quant1(f1[j], s),
                                   quant1(f2[j], s), quant1(f3[j], s));
            tile32[(g * 4 + j) * 17 + cq] = u;
        }
        __syncthreads();
        int base = p * 17 + seg * 4;
        v4i val;
        val[0] = (int)tile32[base + 0];
        val[1] = (int)tile32[base + 1];
        val[2] = (int)tile32[base + 2];
        val[3] = (int)tile32[base + 3];
        *(v4i*)(cxp + (size_t)n * PHW * 64) = val;
    }
}

// ---------------- int8 implicit-GEMM conv: B staged in LDS ----------------
// block = 256 thr = 4 waves, ALL on one o-half: block tile 256 px x 64 o
// wave tile 64 px x 64 o (acc[4][4], same inner structure as R8)
// grid = 392 px-tiles * 2 o-halves = 784 (784%8==0 -> XCD swizzle)
// B: 36 KB in LDS via global_load_lds (one-shot), taps read ds_read_b128
__global__ __launch_bounds__(256) void conv_kernel(const signed char* __restrict__ cx,
                                                   const signed char* __restrict__ wt,
                                                   const float* __restrict__ ax,
                                                   const float* __restrict__ aw,
                                                   float* __restrict__ out) {
    __shared__ signed char bs[WT_HALF];   // [tap][ol][c] = 9*64*64
    float scale = step_size(ax[0]) * step_size(aw[0]);
    int tid  = threadIdx.x;
    int lane = tid & 63;
    int wid  = tid >> 6;    // 0..3: pixel subtile
    int row  = lane & 15;
    int kg   = lane >> 4;

    int bid   = blockIdx.x;
    int swz   = (bid & 7) * 98 + (bid >> 3);   // contiguous chunk per XCD
    int pxt   = swz % 392;
    int ohalf = swz / 392;
    int pbase = pxt * 256 + wid * 64;

    // ---- stage B half (36 KB) into LDS: 9 granule-rounds of 256x16B ----
    const signed char* wsrc = wt + ohalf * WT_HALF;
#pragma unroll
    for (int i = 0; i < 9; ++i) {
        int gbase = i * 256 + wid * 64;        // wave-uniform granule base
        gload_lds16(wsrc + (size_t)(gbase + lane) * 16, bs + gbase * 16);
    }

    // A base pointers while loads fly
    const signed char* xb[4];
#pragma unroll
    for (int pt = 0; pt < 4; ++pt) {
        int p  = pbase + pt * 16 + row;
        int n  = p / HWSZ;
        int hw = p % HWSZ;
        int h  = hw / IMW, wq = hw % IMW;
        xb[pt] = cx + ((size_t)n * PHW + (h + 1) * PADW + (wq + 1)) * 64 + kg * 16;
    }

    asm volatile("s_waitcnt vmcnt(0)" ::: "memory");
    __syncthreads();

    v4i acc[4][4] = {};

#pragma unroll
    for (int tap = 0; tap < 9; ++tap) {
        int doff = ((tap / 3 - 1) * PADW + (tap % 3 - 1)) * 64;
        v4i a[4];
#pragma unroll
        for (int pt = 0; pt < 4; ++pt)
            a[pt] = *(const v4i*)(xb[pt] + doff);
        v4i b[4];
#pragma unroll
        for (int ot = 0; ot < 4; ++ot)
            b[ot] = *(const v4i*)(bs + tap * 4096 + (ot * 16 + row) * 64 + kg * 16);
#pragma unroll
        for (int pt = 0; pt < 4; ++pt)
#pragma unroll
            for (int ot = 0; ot < 4; ++ot)
                acc[pt][ot] = __builtin_amdgcn_mfma_i32_16x16x64_i8(a[pt], b[ot], acc[pt][ot], 0, 0, 0);
    }

    // epilogue: D row = (lane>>4)*4+reg = pixel, col = lane&15 = o(within half)
#pragma unroll
    for (int pt = 0; pt < 4; ++pt) {
        int p4 = pbase + pt * 16 + kg * 4;
        int n  = p4 / HWSZ;
        int hw = p4 % HWSZ;
#pragma unroll
        for (int ot = 0; ot < 4; ++ot) {
            int o = ohalf * 64 + ot * 16 + row;
            v4f v;
            v[0] = scale * (float)acc[pt][ot][0];
            v[1] = scale * (float)acc[pt][ot][1];
            v[2] = scale * (float)acc[pt][ot][2];
            v[3] = scale * (float)acc[pt][ot][3];
            *(v4f*)(out + ((size_t)n * COUT + o) * HWSZ + hw) = v;
        }
    }
}

extern "C" void kernel_launch(void* const* d_in, const int* in_sizes, int n_in,
                              void* d_out, int out_size, void* d_ws, size_t ws_size,
                              hipStream_t stream) {
    const float* x  = (const float*)d_in[0];
    const float* w  = (const float*)d_in[1];
    const float* ax = (const float*)d_in[2];
    const float* aw = (const float*)d_in[3];
    float* out = (float*)d_out;

    signed char* cx = (signed char*)d_ws;   // 32*3364*64 = 6,889,472 B (padded NHWC)
    signed char* wt = cx + 6889472;         // 2*36,864 B  [half][tap][ol][c]

    quant_kernel<<<794, 256, 0, stream>>>(x, w, ax, aw, cx, wt);
    conv_kernel<<<784, 256, 0, stream>>>(cx, wt, ax, aw, out);
}

// Round 12
// 33.250 us; speedup vs baseline: 1.8707x; 1.0862x over previous
//
#include <hip/hip_runtime.h>
#include <hip/hip_bf16.h>

typedef int   v4i __attribute__((ext_vector_type(4)));
typedef float v4f __attribute__((ext_vector_type(4)));

#define HWSZ 3136   // 56*56
#define IMW  56
#define PADW 58     // 56+2 halo
#define PHW  3364   // 58*58
#define CIN  64
#define COUT 128

__device__ __forceinline__ float step_size(float a) {
    a = a > 0.f ? a : 0.f;              // relu(alpha)
    return 2.0f * a / 254.0f;
}

__device__ __forceinline__ int quant1(float x, float s) {
    float v = rintf(x / s);             // round-half-even like jnp.round
    v = fminf(127.f, fmaxf(-127.f, v)); // clip(-127, 127)
    return (int)v;
}

__device__ __forceinline__ unsigned int pack4(int a, int b, int c, int d) {
    return (unsigned int)(a & 255) | ((unsigned int)(b & 255) << 8) |
           ((unsigned int)(c & 255) << 16) | ((unsigned int)(d & 255) << 24);
}

__device__ __forceinline__ void gload_lds16(const signed char* g, signed char* l) {
    __builtin_amdgcn_global_load_lds(
        (const __attribute__((address_space(1))) void*)g,
        (__attribute__((address_space(3))) void*)l, 16, 0, 0);
}

// ---------------- fused quantize ----------------
// blocks 0..391  : x NCHW fp32 -> padded NHWC int8
// blocks 392..679: w OIHW -> wt[tap][o][c]
// blocks 680..793: zero the 1-px halo of cx
__global__ __launch_bounds__(256) void quant_kernel(const float* __restrict__ x,
                                                    const float* __restrict__ w,
                                                    const float* __restrict__ alpha_x,
                                                    const float* __restrict__ alpha_w,
                                                    signed char* __restrict__ cx,
                                                    signed char* __restrict__ wt) {
    int t = threadIdx.x;
    int b = blockIdx.x;
    if (b >= 392) {
        if (b >= 680) {
            int q = (b - 680) * 256 + t;
            int n = q / 912;
            int r = q % 912;
            int px = r >> 2, seg = r & 3;
            int ph, pw;
            if (px < 58)       { ph = 0;  pw = px; }
            else if (px < 116) { ph = 57; pw = px - 58; }
            else { int k = px - 116; ph = 1 + (k >> 1); pw = (k & 1) * 57; }
            v4i z = {0, 0, 0, 0};
            *(v4i*)(cx + ((size_t)n * PHW + ph * PADW + pw) * 64 + seg * 16) = z;
            return;
        }
        float s = step_size(alpha_w[0]);
        int j = (b - 392) * 256 + t;   // wt flat index in [tap][o][c], 73728 total
        int tap = j / 8192;
        int r   = j % 8192;
        int o   = r >> 6;
        int c   = r & 63;
        float v = w[((size_t)o * 64 + c) * 9 + tap];
        wt[j] = (signed char)quant1(v, s);
        return;
    }

    __shared__ unsigned int tile32[64 * 17];
    float s = step_size(alpha_x[0]);
    int nb  = b / 49;
    int hw0 = (b % 49) * 64;
    int g   = t & 15;
    int cq  = t >> 4;
    int p   = t >> 2;
    int seg = t & 3;
    int hw  = hw0 + p;
    int h   = hw / IMW, wq = hw % IMW;
    signed char* cxp = cx + ((size_t)(h + 1) * PADW + (wq + 1)) * 64 + seg * 16;

#pragma unroll
    for (int i = 0; i < 4; ++i) {
        int n = nb * 4 + i;
        const float* xb = x + ((size_t)n * CIN + cq * 4) * HWSZ + hw0 + g * 4;
        v4f f0 = *(const v4f*)(xb);
        v4f f1 = *(const v4f*)(xb + HWSZ);
        v4f f2 = *(const v4f*)(xb + 2 * HWSZ);
        v4f f3 = *(const v4f*)(xb + 3 * HWSZ);
        if (i) __syncthreads();
#pragma unroll
        for (int j = 0; j < 4; ++j) {
            unsigned int u = pack4(quant1(f0[j], s), quant1(f1[j], s),
                                   quant1(f2[j], s), quant1(f3[j], s));
            tile32[(g * 4 + j) * 17 + cq] = u;
        }
        __syncthreads();
        int base = p * 17 + seg * 4;
        v4i val;
        val[0] = (int)tile32[base + 0];
        val[1] = (int)tile32[base + 1];
        val[2] = (int)tile32[base + 2];
        val[3] = (int)tile32[base + 3];
        *(v4i*)(cxp + (size_t)n * PHW * 64) = val;
    }
}

// ---------------- int8 implicit-GEMM conv: A in LDS, B in registers ----------------
// block = 128 thr = 2 waves: 64 px x 128 o (wave = 64 px x 64 o, acc[4][4])
// A: block's 5-padded-row window (18.6 KB) staged via global_load_lds
// B: per-wave 36 x v4i (144 VGPR) preloaded once, pinned vs sinking
// Inner loop: 4 ds_read_b128 + 16 MFMA per tap. ZERO global VMEM in loop.
// grid = 1568 (1568%8==0, XCD swizzle)
__global__ __launch_bounds__(128, 1) void conv_kernel(const signed char* __restrict__ cx,
                                                      const signed char* __restrict__ wt,
                                                      const float* __restrict__ ax,
                                                      const float* __restrict__ aw,
                                                      float* __restrict__ out) {
    __shared__ signed char as_[20480];   // 5 rows * 58 * 64 = 18560, padded to 10*2048
    float scale = step_size(ax[0]) * step_size(aw[0]);
    int tid  = threadIdx.x;
    int lane = tid & 63;
    int wid  = tid >> 6;    // 0..1: o half
    int row  = lane & 15;
    int kg   = lane >> 4;

    int bid   = blockIdx.x;
    int swz   = (bid & 7) * 196 + (bid >> 3);
    int p0    = swz * 64;
    int n     = p0 / HWSZ;
    int hw0   = p0 % HWSZ;
    int h0    = hw0 / IMW;
    int ustart = h0 - 1; if (ustart > 52) ustart = 52;   // unpadded window start
    int pstart = ustart + 1;                              // padded row index 0..53

    // ---- stage A window (rows pstart..pstart+4 of padded image) into LDS ----
    const signed char* wsrc = cx + ((size_t)n * PHW + (size_t)pstart * PADW) * 64;
#pragma unroll
    for (int r = 0; r < 10; ++r) {
        int slotbase = r * 128 + wid * 64;        // wave-uniform
        gload_lds16(wsrc + (size_t)(slotbase + lane) * 16, as_ + slotbase * 16);
    }

    // ---- preload B: 9 taps x 4 o-tiles, 16B/lane each ----
    int obase = wid * 64;
    const signed char* wb = wt + (obase + row) * 64 + kg * 16;
    v4i breg[9][4];
#pragma unroll
    for (int tap = 0; tap < 9; ++tap)
#pragma unroll
        for (int ot = 0; ot < 4; ++ot)
            breg[tap][ot] = *(const v4i*)(wb + tap * (COUT * 64) + ot * (16 * 64));

    // ---- per-lane LDS base addr for each px tile ----
    int lbase[4];
#pragma unroll
    for (int pt = 0; pt < 4; ++pt) {
        int hwp = hw0 + pt * 16 + row;
        int hh  = hwp / IMW, ww = hwp % IMW;
        lbase[pt] = ((hh - ustart) * PADW + (ww + 1)) * 64 + kg * 16;
    }

    asm volatile("s_waitcnt vmcnt(0)" ::: "memory");
    __syncthreads();
    // pin B in registers so the scheduler can't sink the loads into the loop
#pragma unroll
    for (int tap = 0; tap < 9; ++tap)
#pragma unroll
        for (int ot = 0; ot < 4; ++ot)
            asm volatile("" :: "v"(breg[tap][ot]));

    v4i acc[4][4] = {};

#pragma unroll
    for (int tap = 0; tap < 9; ++tap) {
        int doff = ((tap / 3 - 1) * PADW + (tap % 3 - 1)) * 64;
        v4i a[4];
#pragma unroll
        for (int pt = 0; pt < 4; ++pt)
            a[pt] = *(const v4i*)(as_ + lbase[pt] + doff);
#pragma unroll
        for (int pt = 0; pt < 4; ++pt)
#pragma unroll
            for (int ot = 0; ot < 4; ++ot)
                acc[pt][ot] = __builtin_amdgcn_mfma_i32_16x16x64_i8(a[pt], breg[tap][ot], acc[pt][ot], 0, 0, 0);
    }

    // epilogue: D row = (lane>>4)*4+reg = pixel, col = lane&15 = o
#pragma unroll
    for (int pt = 0; pt < 4; ++pt) {
        int hw = hw0 + pt * 16 + kg * 4;
#pragma unroll
        for (int ot = 0; ot < 4; ++ot) {
            int o = obase + ot * 16 + row;
            v4f v;
            v[0] = scale * (float)acc[pt][ot][0];
            v[1] = scale * (float)acc[pt][ot][1];
            v[2] = scale * (float)acc[pt][ot][2];
            v[3] = scale * (float)acc[pt][ot][3];
            *(v4f*)(out + ((size_t)n * COUT + o) * HWSZ + hw) = v;
        }
    }
}

extern "C" void kernel_launch(void* const* d_in, const int* in_sizes, int n_in,
                              void* d_out, int out_size, void* d_ws, size_t ws_size,
                              hipStream_t stream) {
    const float* x  = (const float*)d_in[0];
    const float* w  = (const float*)d_in[1];
    const float* ax = (const float*)d_in[2];
    const float* aw = (const float*)d_in[3];
    float* out = (float*)d_out;

    signed char* cx = (signed char*)d_ws;   // 32*3364*64 = 6,889,472 B (padded NHWC)
    signed char* wt = cx + 6889472;         // 9*128*64   =    73,728 B  [tap][o][c]

    quant_kernel<<<794, 256, 0, stream>>>(x, w, ax, aw, cx, wt);
    conv_kernel<<<1568, 128, 0, stream>>>(cx, wt, ax, aw, out);
}